// Round 1
// baseline (60.483 us; speedup 1.0000x reference)
//
#include <hip/hip_runtime.h>
#include <hip/hip_bf16.h>

#define MASK_PENALTY (-10000)

// One block per batch row. Block-private LDS histogram (X=1024 bins).
// int4-vectorized load/store of the 4096-element row.
__global__ __launch_bounds__(256) void DurationCalculator_87677462380947_kernel(
    const int* __restrict__ duration,       // [B, Y] int32
    const int* __restrict__ output_length,  // [B] int32
    const int* __restrict__ x_steps_p,      // [1] int32 (device-side scalar)
    int* __restrict__ out_wa,               // [B, Y] int32
    int* __restrict__ out_hist,             // [B, X] int32
    int Y)
{
    const int b = blockIdx.x;
    const int len = output_length[b];
    const int x_steps = *x_steps_p;   // 1024 for this problem

    __shared__ int hist[1024];
    for (int i = threadIdx.x; i < x_steps; i += blockDim.x) hist[i] = 0;
    __syncthreads();

    const int4* __restrict__ drow = (const int4*)(duration + (size_t)b * Y);
    int4* __restrict__ warow = (int4*)(out_wa + (size_t)b * Y);
    const int nvec = Y >> 2;  // 1024 int4 per row

    for (int v = threadIdx.x; v < nvec; v += blockDim.x) {
        int4 d = drow[v];
        const int y0 = v << 2;
        int4 w;
        w.x = d.x + ((y0 + 0) < len ? 0 : MASK_PENALTY);
        w.y = d.y + ((y0 + 1) < len ? 0 : MASK_PENALTY);
        w.z = d.z + ((y0 + 2) < len ? 0 : MASK_PENALTY);
        w.w = d.w + ((y0 + 3) < len ? 0 : MASK_PENALTY);
        warow[v] = w;
        // (unsigned)w < x_steps  <=>  0 <= w < x_steps  (masked values are negative)
        if ((unsigned)w.x < (unsigned)x_steps) atomicAdd(&hist[w.x], 1);
        if ((unsigned)w.y < (unsigned)x_steps) atomicAdd(&hist[w.y], 1);
        if ((unsigned)w.z < (unsigned)x_steps) atomicAdd(&hist[w.z], 1);
        if ((unsigned)w.w < (unsigned)x_steps) atomicAdd(&hist[w.w], 1);
    }
    __syncthreads();

    int* __restrict__ orow = out_hist + (size_t)b * x_steps;
    for (int i = threadIdx.x; i < x_steps; i += blockDim.x) orow[i] = hist[i];
}

extern "C" void kernel_launch(void* const* d_in, const int* in_sizes, int n_in,
                              void* d_out, int out_size, void* d_ws, size_t ws_size,
                              hipStream_t stream) {
    const int* duration      = (const int*)d_in[0];  // B*Y
    const int* output_length = (const int*)d_in[1];  // B
    const int* x_steps_p     = (const int*)d_in[2];  // scalar (1024)

    const int B = in_sizes[1];
    const int Y = in_sizes[0] / B;                   // 4096
    const int X = (out_size - in_sizes[0]) / B;      // 1024

    int* out_wa   = (int*)d_out;                     // first B*Y ints
    int* out_hist = (int*)d_out + (size_t)B * Y;     // then B*X ints
    (void)X; (void)n_in; (void)d_ws; (void)ws_size;

    DurationCalculator_87677462380947_kernel<<<B, 256, 0, stream>>>(
        duration, output_length, x_steps_p, out_wa, out_hist, Y);
}

// Round 2
// 59.477 us; speedup vs baseline: 1.0169x; 1.0169x over previous
//
#include <hip/hip_runtime.h>
#include <hip/hip_bf16.h>

#define MASK_PENALTY (-10000)

// One block per batch row, 1024 threads (16 waves). Each thread handles
// exactly one int4 (4 elements) of the 4096-element row: load -> mask-add ->
// store weights_argmax -> LDS-histogram. Hist flushed by direct store (full
// overwrite, so no zero-init of the output region needed).
__global__ __launch_bounds__(1024) void DurationCalculator_87677462380947_kernel(
    const int* __restrict__ duration,       // [B, Y] int32
    const int* __restrict__ output_length,  // [B] int32
    const int* __restrict__ x_steps_p,      // [1] int32 (device-side scalar)
    int* __restrict__ out_wa,               // [B, Y] int32
    int* __restrict__ out_hist,             // [B, X] int32
    int Y)
{
    const int b = blockIdx.x;
    const int len = output_length[b];
    const int x_steps = *x_steps_p;   // 1024 for this problem

    __shared__ int hist[1024];
    for (int i = threadIdx.x; i < x_steps; i += blockDim.x) hist[i] = 0;
    __syncthreads();

    const int4* __restrict__ drow = (const int4*)(duration + (size_t)b * Y);
    int4* __restrict__ warow = (int4*)(out_wa + (size_t)b * Y);
    const int nvec = Y >> 2;  // 1024 int4 per row; blockDim=1024 -> 1 per thread

    for (int v = threadIdx.x; v < nvec; v += blockDim.x) {
        int4 d = drow[v];
        const int y0 = v << 2;
        int4 w;
        w.x = d.x + ((y0 + 0) < len ? 0 : MASK_PENALTY);
        w.y = d.y + ((y0 + 1) < len ? 0 : MASK_PENALTY);
        w.z = d.z + ((y0 + 2) < len ? 0 : MASK_PENALTY);
        w.w = d.w + ((y0 + 3) < len ? 0 : MASK_PENALTY);
        warow[v] = w;
        // (unsigned)w < x_steps  <=>  0 <= w < x_steps  (masked values are negative)
        if ((unsigned)w.x < (unsigned)x_steps) atomicAdd(&hist[w.x], 1);
        if ((unsigned)w.y < (unsigned)x_steps) atomicAdd(&hist[w.y], 1);
        if ((unsigned)w.z < (unsigned)x_steps) atomicAdd(&hist[w.z], 1);
        if ((unsigned)w.w < (unsigned)x_steps) atomicAdd(&hist[w.w], 1);
    }
    __syncthreads();

    int* __restrict__ orow = out_hist + (size_t)b * x_steps;
    for (int i = threadIdx.x; i < x_steps; i += blockDim.x) orow[i] = hist[i];
}

extern "C" void kernel_launch(void* const* d_in, const int* in_sizes, int n_in,
                              void* d_out, int out_size, void* d_ws, size_t ws_size,
                              hipStream_t stream) {
    const int* duration      = (const int*)d_in[0];  // B*Y
    const int* output_length = (const int*)d_in[1];  // B
    const int* x_steps_p     = (const int*)d_in[2];  // scalar (1024)

    const int B = in_sizes[1];
    const int Y = in_sizes[0] / B;                   // 4096
    const int X = (out_size - in_sizes[0]) / B;      // 1024

    int* out_wa   = (int*)d_out;                     // first B*Y ints
    int* out_hist = (int*)d_out + (size_t)B * Y;     // then B*X ints
    (void)X; (void)n_in; (void)d_ws; (void)ws_size;

    DurationCalculator_87677462380947_kernel<<<B, 1024, 0, stream>>>(
        duration, output_length, x_steps_p, out_wa, out_hist, Y);
}

// Round 3
// 59.051 us; speedup vs baseline: 1.0243x; 1.0072x over previous
//
#include <hip/hip_runtime.h>
#include <hip/hip_bf16.h>

#define MASK_PENALTY (-10000)

// One block per batch row, 1024 threads (16 waves). Each thread handles
// exactly one int4 (4 elements) of the 4096-element row.
// Latency-ordering: the global int4 load and the two scalar loads are issued
// BEFORE the LDS zero-init + barrier, so HBM latency overlaps the init
// instead of being serialized behind s_barrier.
__global__ __launch_bounds__(1024) void DurationCalculator_87677462380947_kernel(
    const int* __restrict__ duration,       // [B, Y] int32
    const int* __restrict__ output_length,  // [B] int32
    const int* __restrict__ x_steps_p,      // [1] int32 (device-side scalar)
    int* __restrict__ out_wa,               // [B, Y] int32
    int* __restrict__ out_hist,             // [B, X] int32
    int Y)
{
    const int b = blockIdx.x;
    const int v = threadIdx.x;              // 0..1023, one int4 per thread

    // Issue all loads up front (before any barrier) so latency overlaps init.
    const int4* __restrict__ drow = (const int4*)(duration + (size_t)b * Y);
    int4 d = drow[v];                       // global load issues here
    const int len = output_length[b];
    const int x_steps = *x_steps_p;         // 1024 for this problem

    __shared__ int hist[1024];
    for (int i = threadIdx.x; i < x_steps; i += blockDim.x) hist[i] = 0;
    __syncthreads();

    const int y0 = v << 2;
    int4 w;
    w.x = d.x + ((y0 + 0) < len ? 0 : MASK_PENALTY);
    w.y = d.y + ((y0 + 1) < len ? 0 : MASK_PENALTY);
    w.z = d.z + ((y0 + 2) < len ? 0 : MASK_PENALTY);
    w.w = d.w + ((y0 + 3) < len ? 0 : MASK_PENALTY);

    // Store first so the VMEM write drains while LDS atomics run.
    int4* __restrict__ warow = (int4*)(out_wa + (size_t)b * Y);
    warow[v] = w;

    // (unsigned)w < x_steps  <=>  0 <= w < x_steps  (masked values are negative)
    if ((unsigned)w.x < (unsigned)x_steps) atomicAdd(&hist[w.x], 1);
    if ((unsigned)w.y < (unsigned)x_steps) atomicAdd(&hist[w.y], 1);
    if ((unsigned)w.z < (unsigned)x_steps) atomicAdd(&hist[w.z], 1);
    if ((unsigned)w.w < (unsigned)x_steps) atomicAdd(&hist[w.w], 1);
    __syncthreads();

    int* __restrict__ orow = out_hist + (size_t)b * x_steps;
    for (int i = threadIdx.x; i < x_steps; i += blockDim.x) orow[i] = hist[i];
}

extern "C" void kernel_launch(void* const* d_in, const int* in_sizes, int n_in,
                              void* d_out, int out_size, void* d_ws, size_t ws_size,
                              hipStream_t stream) {
    const int* duration      = (const int*)d_in[0];  // B*Y
    const int* output_length = (const int*)d_in[1];  // B
    const int* x_steps_p     = (const int*)d_in[2];  // scalar (1024)

    const int B = in_sizes[1];
    const int Y = in_sizes[0] / B;                   // 4096
    const int X = (out_size - in_sizes[0]) / B;      // 1024

    int* out_wa   = (int*)d_out;                     // first B*Y ints
    int* out_hist = (int*)d_out + (size_t)B * Y;     // then B*X ints
    (void)X; (void)n_in; (void)d_ws; (void)ws_size;

    DurationCalculator_87677462380947_kernel<<<B, 1024, 0, stream>>>(
        duration, output_length, x_steps_p, out_wa, out_hist, Y);
}